// Round 9
// baseline (33806.088 us; speedup 1.0000x reference)
//
#include <hip/hip_runtime.h>
#include <hip/hip_bf16.h>

#define B_SZ   256
#define T_SZ   256
#define FUT    32
#define TF_SZ  (T_SZ + FUT)
#define HIDN   1024
#define INDIM  64
#define OUTDIM 64
#define NBLK   256

typedef __attribute__((ext_vector_type(8))) short bf16x8;
typedef __attribute__((ext_vector_type(4))) float f32x4;

__device__ __forceinline__ float bf2f(unsigned short u) {
    union { unsigned int i; float f; } v; v.i = (unsigned int)u << 16; return v.f;
}
__device__ __forceinline__ unsigned short f2bf(float f) {
    union { float f; unsigned int i; } v; v.f = f;
    unsigned int r = v.i + 0x7FFFu + ((v.i >> 16) & 1u);
    return (unsigned short)(r >> 16);
}
__device__ __forceinline__ float sigm(float x) { return 1.0f / (1.0f + __expf(-x)); }

// Coherent (L2-bypassing, L3-served) 16B load as 2x u64 agent-scope atomics.
__device__ __forceinline__ bf16x8 ld_h(const unsigned short* p) {
    unsigned long long a = __hip_atomic_load((const unsigned long long*)p,
                                             __ATOMIC_RELAXED, __HIP_MEMORY_SCOPE_AGENT);
    unsigned long long b = __hip_atomic_load((const unsigned long long*)p + 1,
                                             __ATOMIC_RELAXED, __HIP_MEMORY_SCOPE_AGENT);
    union { unsigned long long q[2]; bf16x8 v; } u;
    u.q[0] = a; u.q[1] = b;
    return u.v;
}
// Coherent packed store of two adjacent bf16 (write-through, agent scope).
__device__ __forceinline__ void st_h2(unsigned short* p, unsigned short lo, unsigned short hi) {
    unsigned int w = (unsigned int)lo | ((unsigned int)hi << 16);
    __hip_atomic_store((unsigned int*)p, w, __ATOMIC_RELAXED, __HIP_MEMORY_SCOPE_AGENT);
}

// Grid barrier: NO cache maintenance. Monotone counter, relaxed atomics.
// h exchange is via sc1 atomics (L3-coherent), so only waitcnt + count order
// are needed. Workgroup fences = compiler ordering only (no wbl2/inv).
__device__ __forceinline__ void gbarrier(unsigned int* bar, unsigned int bidx) {
    __syncthreads();
    if (threadIdx.x == 0) {
        __builtin_amdgcn_fence(__ATOMIC_RELEASE, "workgroup");
        __builtin_amdgcn_s_waitcnt(0);                 // h stores acked at L3
        __hip_atomic_fetch_add(&bar[0], 1u, __ATOMIC_RELAXED,
                               __HIP_MEMORY_SCOPE_AGENT);
        const unsigned int tgt = bidx * (unsigned int)NBLK;
        while (__hip_atomic_load(&bar[0], __ATOMIC_RELAXED,
                                 __HIP_MEMORY_SCOPE_AGENT) < tgt)
            __builtin_amdgcn_s_sleep(1);
        __builtin_amdgcn_fence(__ATOMIC_ACQUIRE, "workgroup");
    }
    __syncthreads();
}

// ---------------------------------------------------------------------------
// Persistent 2-layer LSTM. 256 blocks x 512 threads (1 block/CU).
// Block owns 4 hidden units x 4 gates = 16 gate-rows (one A-fragment), all
// 256 batch rows. Weights register-resident (52 VGPR). Cell state in regs.
// All h / x-feedback traffic via agent-scope atomics (sc1) -> no fences.
// Merged superphase: {fold out(t-1) | L2(t) | L1(t+1)} -> 1 barrier/step.
// ---------------------------------------------------------------------------
__global__ __attribute__((amdgpu_flat_work_group_size(512, 512),
                          amdgpu_waves_per_eu(2, 2)))
void lstm_persist(
    const unsigned short* __restrict__ xbf,    // [256][256][64]
    unsigned short* __restrict__ xfut,         // [256][64]
    const unsigned short* __restrict__ W1,     // [4096][1088]
    const unsigned short* __restrict__ W2,     // [4096][2048]
    const unsigned short* __restrict__ Wlin,   // [64][1024]
    const unsigned short* __restrict__ Wo2i,   // [64][64]
    const float* __restrict__ b_ih1, const float* __restrict__ b_hh1,
    const float* __restrict__ b_ih2, const float* __restrict__ b_hh2,
    const float* __restrict__ blin, const float* __restrict__ bo2i,
    unsigned short* __restrict__ hh0,          // [256][2048] = [h1|h2]
    unsigned short* __restrict__ hh1,
    float* __restrict__ outp,                  // [256][288][64] f32
    unsigned int* __restrict__ bar)
{
    __shared__ float part[8][16][258];
    __shared__ float red[512];
    __shared__ float blds[32];

    const int tid  = threadIdx.x;
    const int id   = blockIdx.x;
    const int ug   = (id & 7) * 32 + (id >> 3);   // XCD-contiguous unit group
    const int jb   = ug * 4;
    const int ks   = tid >> 6;
    const int lane = tid & 63;
    const int am   = lane & 15, ah = lane >> 4;

    if (tid < 32) {
        const int L = tid >> 4, G = (tid >> 2) & 3, q = tid & 3;
        const int j = jb + q;
        blds[tid] = L ? (b_ih2[G * HIDN + j] + b_hh2[G * HIDN + j])
                      : (b_ih1[G * HIDN + j] + b_hh1[G * HIDN + j]);
    }

    const int wr = (am >> 2) * 1024 + jb + (am & 3);

    bf16x8 w2r[8];
    {
        const size_t b0 = (size_t)wr * 2048 + ks * 256 + ah * 8;
#pragma unroll
        for (int kk = 0; kk < 8; ++kk)
            w2r[kk] = *(const bf16x8*)(W2 + b0 + kk * 32);
    }
    const int kb1 = (ks < 2) ? ks * 160 : 320 + (ks - 2) * 128;
    const int kc1 = (ks < 2) ? 5 : 4;
    bf16x8 w1r[5];
#pragma unroll
    for (int kk = 0; kk < 5; ++kk) w1r[kk] = (bf16x8){0,0,0,0,0,0,0,0};
    {
        const size_t b0 = (size_t)wr * 1088 + kb1 + ah * 8;
#pragma unroll
        for (int kk = 0; kk < 5; ++kk) if (kk < kc1)
            w1r[kk] = *(const bf16x8*)(W1 + b0 + kk * 32);
    }

    // epilogue: thread handles units u0=2*jqA, u1=u0+1 for batch row bl
    const int jqA = tid >> 8;          // 0..1
    const int bl  = tid & 255;
    const int u0  = 2 * jqA, u1 = u0 + 1;
    float c1a = 0.f, c1b = 0.f, c2a = 0.f, c2b = 0.f;

    const int fc = id & 63, fq = id >> 6;
    const int frow = tid & 63, fkq = tid >> 6;
    __syncthreads();

    unsigned int bidx = 0;

    auto l1_phase = [&](const unsigned short* xsrc, const unsigned short* hsrc,
                        unsigned short* hdst) {
#pragma unroll 1
        for (int np = 0; np < 16; ++np) {
            const int brow = np * 16 + am;
            bf16x8 f[5];
#pragma unroll
            for (int kk = 0; kk < 5; ++kk) if (kk < kc1) {
                const int k = kb1 + kk * 32 + ah * 8;
                f[kk] = (k < 64)
                    ? ld_h(xsrc + (size_t)brow * INDIM + k)
                    : ld_h(hsrc + (size_t)brow * 2048 + (k - 64));
            }
            f32x4 pe = {0,0,0,0}, po = {0,0,0,0};
#pragma unroll
            for (int kk = 0; kk < 5; ++kk) if (kk < kc1) {
                if (kk & 1) po = __builtin_amdgcn_mfma_f32_16x16x32_bf16(w1r[kk], f[kk], po, 0, 0, 0);
                else        pe = __builtin_amdgcn_mfma_f32_16x16x32_bf16(w1r[kk], f[kk], pe, 0, 0, 0);
            }
#pragma unroll
            for (int r = 0; r < 4; ++r)
                part[ks][ah * 4 + r][np * 16 + am] = pe[r] + po[r];
        }
        __syncthreads();
        {
            float g0a = 0.f, g1a = 0.f, g2a = 0.f, g3a = 0.f;
            float g0b = 0.f, g1b = 0.f, g2b = 0.f, g3b = 0.f;
#pragma unroll
            for (int s = 0; s < 8; ++s) {
                g0a += part[s][u0][bl];      g1a += part[s][4 + u0][bl];
                g2a += part[s][8 + u0][bl];  g3a += part[s][12 + u0][bl];
                g0b += part[s][u1][bl];      g1b += part[s][4 + u1][bl];
                g2b += part[s][8 + u1][bl];  g3b += part[s][12 + u1][bl];
            }
            const float gia = sigm(g0a + blds[u0]),      gfa = sigm(g1a + blds[4 + u0]);
            const float gga = tanhf(g2a + blds[8 + u0]), goa = sigm(g3a + blds[12 + u0]);
            c1a = gfa * c1a + gia * gga;
            const float gib = sigm(g0b + blds[u1]),      gfb = sigm(g1b + blds[4 + u1]);
            const float ggb = tanhf(g2b + blds[8 + u1]), gob = sigm(g3b + blds[12 + u1]);
            c1b = gfb * c1b + gib * ggb;
            st_h2(hdst + (size_t)bl * 2048 + jb + u0,
                  f2bf(goa * tanhf(c1a)), f2bf(gob * tanhf(c1b)));
        }
        __syncthreads();
    };

    auto l2_phase = [&](const unsigned short* hsrc, unsigned short* hdst) {
#pragma unroll 1
        for (int np = 0; np < 16; ++np) {
            const int brow = np * 16 + am;
            const unsigned short* bp = hsrc + (size_t)brow * 2048 + ks * 256 + ah * 8;
            bf16x8 f[8];
#pragma unroll
            for (int kk = 0; kk < 8; ++kk)
                f[kk] = ld_h(bp + kk * 32);
            f32x4 pe = {0,0,0,0}, po = {0,0,0,0};
#pragma unroll
            for (int kk = 0; kk < 8; ++kk) {
                if (kk & 1) po = __builtin_amdgcn_mfma_f32_16x16x32_bf16(w2r[kk], f[kk], po, 0, 0, 0);
                else        pe = __builtin_amdgcn_mfma_f32_16x16x32_bf16(w2r[kk], f[kk], pe, 0, 0, 0);
            }
#pragma unroll
            for (int r = 0; r < 4; ++r)
                part[ks][ah * 4 + r][np * 16 + am] = pe[r] + po[r];
        }
        __syncthreads();
        {
            float g0a = 0.f, g1a = 0.f, g2a = 0.f, g3a = 0.f;
            float g0b = 0.f, g1b = 0.f, g2b = 0.f, g3b = 0.f;
#pragma unroll
            for (int s = 0; s < 8; ++s) {
                g0a += part[s][u0][bl];      g1a += part[s][4 + u0][bl];
                g2a += part[s][8 + u0][bl];  g3a += part[s][12 + u0][bl];
                g0b += part[s][u1][bl];      g1b += part[s][4 + u1][bl];
                g2b += part[s][8 + u1][bl];  g3b += part[s][12 + u1][bl];
            }
            const float gia = sigm(g0a + blds[16 + u0]),      gfa = sigm(g1a + blds[20 + u0]);
            const float gga = tanhf(g2a + blds[24 + u0]), goa = sigm(g3a + blds[28 + u0]);
            c2a = gfa * c2a + gia * gga;
            const float gib = sigm(g0b + blds[16 + u1]),      gfb = sigm(g1b + blds[20 + u1]);
            const float ggb = tanhf(g2b + blds[24 + u1]), gob = sigm(g3b + blds[28 + u1]);
            c2b = gfb * c2b + gib * ggb;
            st_h2(hdst + (size_t)bl * 2048 + 1024 + jb + u0,
                  f2bf(goa * tanhf(c2a)), f2bf(gob * tanhf(c2b)));
        }
        __syncthreads();
    };

    auto fold = [&](int tm1, const unsigned short* hsrc) {
        const unsigned short* hp = hsrc + (size_t)(fq * 64 + frow) * 2048 + 1024 + fkq * 128;
        const unsigned short* wp = Wlin + (size_t)fc * 1024 + fkq * 128;
        float p = 0.f;
#pragma unroll
        for (int k = 0; k < 128; k += 8) {
            bf16x8 hv = ld_h(hp + k);
            bf16x8 wv = *(const bf16x8*)(wp + k);
#pragma unroll
            for (int u = 0; u < 8; ++u)
                p += bf2f((unsigned short)hv[u]) * bf2f((unsigned short)wv[u]);
        }
        red[fkq * 64 + frow] = p;
        __syncthreads();
        if (tid < 64) {
            float s = blin[fc];
#pragma unroll
            for (int u = 0; u < 8; ++u) s += red[u * 64 + tid];
            outp[((size_t)(fq * 64 + tid) * TF_SZ + tm1) * OUTDIM + fc] = s;
        }
        __syncthreads();
    };

    auto tail_out = [&](int t, const unsigned short* hnew, int do_fb) {
        if (id < 32) {
            unsigned short* h2s = (unsigned short*)&part[0][0][0];  // [8][1024]
            float* xstage = (float*)((char*)&part[0][0][0] + 16384); // [8][64]
            const int rowbase = id * 8;
            for (int i = tid; i < 1024; i += 512) {
                const int rr = i >> 7, k8 = (i & 127) * 8;
                bf16x8 hv = ld_h(hnew + (size_t)(rowbase + rr) * 2048 + 1024 + k8);
                *(bf16x8*)&h2s[rr * 1024 + k8] = hv;
            }
            __syncthreads();
            const int rl = tid >> 6, col = tid & 63;
            float acc = blin[col];
            const unsigned short* wl = Wlin + (size_t)col * HIDN;
            for (int k = 0; k < HIDN; k += 8) {
                bf16x8 hv = *(const bf16x8*)&h2s[rl * 1024 + k];
                bf16x8 wv = *(const bf16x8*)&wl[k];
#pragma unroll
                for (int u = 0; u < 8; ++u)
                    acc += bf2f((unsigned short)hv[u]) * bf2f((unsigned short)wv[u]);
            }
            outp[((size_t)(rowbase + rl) * TF_SZ + t) * OUTDIM + col] = acc;
            if (do_fb) {
                red[rl * 64 + col] = acc;
                __syncthreads();
                float x = bo2i[col];
                const unsigned short* w2 = Wo2i + (size_t)col * OUTDIM;
#pragma unroll 8
                for (int jj = 0; jj < OUTDIM; ++jj)
                    x += red[rl * 64 + jj] * bf2f(w2[jj]);
                xstage[rl * 64 + col] = x;
                __syncthreads();
                if (col < 32) {
                    st_h2(xfut + (size_t)(rowbase + rl) * INDIM + col * 2,
                          f2bf(xstage[rl * 64 + col * 2]),
                          f2bf(xstage[rl * 64 + col * 2 + 1]));
                }
            }
        }
    };

    // ================= schedule =================
    l1_phase(xbf, hh0, hh1);
    gbarrier(bar, ++bidx);

    for (int t = 0; t < T_SZ - 1; ++t) {
        const unsigned short* hsrc = ((t + 1) & 1) ? hh1 : hh0;
        unsigned short*       hdst = (t & 1) ? hh1 : hh0;
        if (t >= 1) fold(t - 1, hsrc);
        l2_phase(hsrc, hdst);
        l1_phase(xbf + (size_t)(t + 1) * B_SZ * INDIM, hsrc, hdst);
        gbarrier(bar, ++bidx);
    }

    for (int t = T_SZ - 1; t < TF_SZ; ++t) {
        const unsigned short* hsrc = ((t + 1) & 1) ? hh1 : hh0;
        unsigned short*       hdst = (t & 1) ? hh1 : hh0;
        if (t == T_SZ - 1) fold(t - 1, hsrc);
        l2_phase(hsrc, hdst);
        gbarrier(bar, ++bidx);
        tail_out(t, hdst, t < TF_SZ - 1);
        if (t < TF_SZ - 1) {
            gbarrier(bar, ++bidx);
            l1_phase(xfut, hsrc, hdst);
            gbarrier(bar, ++bidx);
        }
    }
}

__global__ void conv_strided(const float* __restrict__ src,
                             unsigned short* __restrict__ dst,
                             int cols, int dstride, int doff, int total)
{
    const int idx = blockIdx.x * 256 + threadIdx.x;
    if (idx >= total) return;
    const int r = idx / cols, c = idx - r * cols;
    dst[(size_t)r * dstride + doff + c] = f2bf(src[idx]);
}

__global__ void conv_x(const float* __restrict__ src,
                       unsigned short* __restrict__ dst)
{
    const int idx = blockIdx.x * 256 + threadIdx.x;
    const int f = idx & 63, t = (idx >> 6) & 255, b = idx >> 14;
    dst[((size_t)t * B_SZ + b) * INDIM + f] = f2bf(src[idx]);
}

extern "C" void kernel_launch(void* const* d_in, const int* in_sizes, int n_in,
                              void* d_out, int out_size, void* d_ws, size_t ws_size,
                              hipStream_t stream)
{
    const float* input = (const float*)d_in[0];
    const float* W_ih1 = (const float*)d_in[1];
    const float* W_hh1 = (const float*)d_in[2];
    const float* b_ih1 = (const float*)d_in[3];
    const float* b_hh1 = (const float*)d_in[4];
    const float* W_ih2 = (const float*)d_in[5];
    const float* W_hh2 = (const float*)d_in[6];
    const float* b_ih2 = (const float*)d_in[7];
    const float* b_hh2 = (const float*)d_in[8];
    const float* W_lin = (const float*)d_in[9];
    const float* b_lin = (const float*)d_in[10];
    const float* W_o2i = (const float*)d_in[11];
    const float* b_o2i = (const float*)d_in[12];
    float* outp = (float*)d_out;

    char* ws = (char*)d_ws;
    unsigned short* Wcat1 = (unsigned short*)ws; ws += (size_t)4096 * 1088 * 2;
    unsigned short* Wcat2 = (unsigned short*)ws; ws += (size_t)4096 * 2048 * 2;
    unsigned short* Wlinb = (unsigned short*)ws; ws += (size_t)64 * 1024 * 2;
    unsigned short* Wo2ib = (unsigned short*)ws; ws += (size_t)64 * 64 * 2;
    unsigned short* xbf   = (unsigned short*)ws; ws += (size_t)T_SZ * B_SZ * INDIM * 2;
    unsigned short* hh0   = (unsigned short*)ws; ws += (size_t)B_SZ * 2 * HIDN * 2;
    unsigned short* hh1   = (unsigned short*)ws; ws += (size_t)B_SZ * 2 * HIDN * 2;
    unsigned short* xfut  = (unsigned short*)ws; ws += (size_t)B_SZ * INDIM * 2;
    ws = (char*)(((size_t)ws + 255) & ~(size_t)255);
    unsigned int*   bar   = (unsigned int*)ws;   ws += 256;

    conv_strided<<<(4096 * 64 + 255) / 256, 256, 0, stream>>>(W_ih1, Wcat1, 64, 1088, 0, 4096 * 64);
    conv_strided<<<(4096 * 1024 + 255) / 256, 256, 0, stream>>>(W_hh1, Wcat1, 1024, 1088, 64, 4096 * 1024);
    conv_strided<<<(4096 * 1024 + 255) / 256, 256, 0, stream>>>(W_ih2, Wcat2, 1024, 2048, 0, 4096 * 1024);
    conv_strided<<<(4096 * 1024 + 255) / 256, 256, 0, stream>>>(W_hh2, Wcat2, 1024, 2048, 1024, 4096 * 1024);
    conv_strided<<<(64 * 1024 + 255) / 256, 256, 0, stream>>>(W_lin, Wlinb, 1024, 1024, 0, 64 * 1024);
    conv_strided<<<(64 * 64 + 255) / 256, 256, 0, stream>>>(W_o2i, Wo2ib, 64, 64, 0, 64 * 64);
    conv_x<<<(T_SZ * B_SZ * INDIM) / 256, 256, 0, stream>>>(input, xbf);

    hipMemsetAsync(hh0, 0, (size_t)B_SZ * 2 * HIDN * 2, stream);
    hipMemsetAsync(hh1, 0, (size_t)B_SZ * 2 * HIDN * 2, stream);
    hipMemsetAsync(bar, 0, 256, stream);

    void* kargs[] = {
        (void*)&xbf, (void*)&xfut, (void*)&Wcat1, (void*)&Wcat2,
        (void*)&Wlinb, (void*)&Wo2ib,
        (void*)&b_ih1, (void*)&b_hh1, (void*)&b_ih2, (void*)&b_hh2,
        (void*)&b_lin, (void*)&b_o2i,
        (void*)&hh0, (void*)&hh1, (void*)&outp, (void*)&bar
    };
    hipLaunchCooperativeKernel((void*)lstm_persist, dim3(NBLK), dim3(512),
                               kargs, 0, stream);
}

// Round 10
// 20366.603 us; speedup vs baseline: 1.6599x; 1.6599x over previous
//
#include <hip/hip_runtime.h>
#include <hip/hip_bf16.h>

#define B_SZ   256
#define T_SZ   256
#define FUT    32
#define TF_SZ  (T_SZ + FUT)
#define HIDN   1024
#define INDIM  64
#define OUTDIM 64
#define NBLK   256
// s_getreg encoding: id=20 (HW_REG_XCC_ID), offset=0, size=32 -> (31<<11)|20
#define HWREG_XCC ((31u << 11) | 20u)

// bar[] layout (u32 indices)
#define GARR   0    // [8]  per-group monotone arrive counters
#define GFLAG  8    // [8]  per-group "all arrived" flags
#define EP     16   //      global epoch
#define INVD   24   // [16] per-XCD invalidate-done flags
#define XCNT   40   // [16] census counters

typedef __attribute__((ext_vector_type(8))) short bf16x8;
typedef __attribute__((ext_vector_type(4))) float f32x4;

__device__ __forceinline__ float bf2f(unsigned short u) {
    union { unsigned int i; float f; } v; v.i = (unsigned int)u << 16; return v.f;
}
__device__ __forceinline__ unsigned short f2bf(float f) {
    union { float f; unsigned int i; } v; v.f = f;
    unsigned int r = v.i + 0x7FFFu + ((v.i >> 16) & 1u);
    return (unsigned short)(r >> 16);
}
__device__ __forceinline__ float sigm(float x) { return 1.0f / (1.0f + __expf(-x)); }

__device__ __forceinline__ unsigned int ld_rlx(const unsigned int* p) {
    return __hip_atomic_load(p, __ATOMIC_RELAXED, __HIP_MEMORY_SCOPE_AGENT);
}
__device__ __forceinline__ void st_rlx(unsigned int* p, unsigned int v) {
    __hip_atomic_store(p, v, __ATOMIC_RELAXED, __HIP_MEMORY_SCOPE_AGENT);
}
// write-through (L2-bypassing) stores: two bf16 packed / one f32
__device__ __forceinline__ void st_h2(unsigned short* p, unsigned short lo, unsigned short hi) {
    st_rlx((unsigned int*)p, (unsigned int)lo | ((unsigned int)hi << 16));
}
__device__ __forceinline__ void st_f32(float* p, float v) {
    union { float f; unsigned int i; } u; u.f = v;
    st_rlx((unsigned int*)p, u.i);
}

// ---------------------------------------------------------------------------
// Tree grid barrier. Stores are write-through (sc1) so release = waitcnt only.
// Arrive: 32 RMWs per group counter (8 groups in parallel) -> group flag ->
// epoch flag. Acquire: census-elected leader per physical XCD does ONE
// buffer_inv sc1 (L1+L2); members spin done-flag then L1-only buffer_inv.
// ---------------------------------------------------------------------------
__device__ __forceinline__ void gbarrier(unsigned int* bar, unsigned int bidx,
                                         int grp, int xcc, int leader) {
    __syncthreads();
    if (threadIdx.x == 0) {
        __builtin_amdgcn_fence(__ATOMIC_RELEASE, "workgroup");   // compiler order
        __builtin_amdgcn_s_waitcnt(0);             // my sc1 stores are at L3
        unsigned int a = __hip_atomic_fetch_add(&bar[GARR + grp], 1u,
                             __ATOMIC_RELAXED, __HIP_MEMORY_SCOPE_AGENT);
        if (a == bidx * 32u - 1u) {                // last of my group
            st_rlx(&bar[GFLAG + grp], bidx);
            if (grp == (int)(bidx & 7u)) {         // rotating closer
                for (int j = 0; j < 8; ++j)
                    while (ld_rlx(&bar[GFLAG + j]) < bidx)
                        __builtin_amdgcn_s_sleep(1);
                st_rlx(&bar[EP], bidx);
            }
        }
        while (ld_rlx(&bar[EP]) < bidx) __builtin_amdgcn_s_sleep(1);
        if (leader) {
            asm volatile("buffer_inv sc1\n\ts_waitcnt vmcnt(0)" ::: "memory");
            st_rlx(&bar[INVD + xcc], bidx);
        } else {
            while (ld_rlx(&bar[INVD + xcc]) < bidx) __builtin_amdgcn_s_sleep(1);
            asm volatile("buffer_inv\n\ts_waitcnt vmcnt(0)" ::: "memory");
        }
        __builtin_amdgcn_fence(__ATOMIC_ACQUIRE, "workgroup");   // compiler order
    }
    __syncthreads();
}

// ---------------------------------------------------------------------------
// Persistent 2-layer LSTM. 256 blocks x 512 threads (1 block/CU).
// Block owns 4 hidden units x 4 gates = 16 gate-rows (one A-fragment), all
// 256 batch rows. Weights register-resident (52 VGPR). Cell state in regs.
// h exchange: sc1 write-through stores + cached loads + 1 L2-inv/XCD/step.
// Merged superphase: {fold out(t-1) | L2(t) | L1(t+1)} -> 1 barrier/step.
// ---------------------------------------------------------------------------
__global__ __attribute__((amdgpu_flat_work_group_size(512, 512),
                          amdgpu_waves_per_eu(2, 2)))
void lstm_persist(
    const unsigned short* __restrict__ xbf,    // [256][256][64]
    unsigned short* __restrict__ xfut,         // [256][64]
    const unsigned short* __restrict__ W1,     // [4096][1088]
    const unsigned short* __restrict__ W2,     // [4096][2048]
    const unsigned short* __restrict__ Wlin,   // [64][1024]
    const unsigned short* __restrict__ Wo2i,   // [64][64]
    const float* __restrict__ b_ih1, const float* __restrict__ b_hh1,
    const float* __restrict__ b_ih2, const float* __restrict__ b_hh2,
    const float* __restrict__ blin, const float* __restrict__ bo2i,
    unsigned short* __restrict__ hh0,          // [256][2048] = [h1|h2]
    unsigned short* __restrict__ hh1,
    float* __restrict__ outp,                  // [256][288][64] f32
    unsigned int* __restrict__ bar)
{
    __shared__ float part[8][16][258];
    __shared__ float red[512];
    __shared__ float blds[32];

    const int tid  = threadIdx.x;
    const int id   = blockIdx.x;
    const int ug   = (id & 7) * 32 + (id >> 3);   // XCD-contiguous unit group
    const int jb   = ug * 4;
    const int ks   = tid >> 6;
    const int lane = tid & 63;
    const int am   = lane & 15, ah = lane >> 4;
    const int grp  = id >> 5;

    // census: physical XCD + leader election (once)
    int xcc = 0, leader = 0;
    if (tid == 0) {
        xcc = (int)(__builtin_amdgcn_s_getreg(HWREG_XCC) & 15u);
        unsigned int p = __hip_atomic_fetch_add(&bar[XCNT + xcc], 1u,
                             __ATOMIC_RELAXED, __HIP_MEMORY_SCOPE_AGENT);
        leader = (p == 0u);
    }

    if (tid < 32) {
        const int L = tid >> 4, G = (tid >> 2) & 3, q = tid & 3;
        const int j = jb + q;
        blds[tid] = L ? (b_ih2[G * HIDN + j] + b_hh2[G * HIDN + j])
                      : (b_ih1[G * HIDN + j] + b_hh1[G * HIDN + j]);
    }

    const int wr = (am >> 2) * 1024 + jb + (am & 3);

    bf16x8 w2r[8];
    {
        const size_t b0 = (size_t)wr * 2048 + ks * 256 + ah * 8;
#pragma unroll
        for (int kk = 0; kk < 8; ++kk)
            w2r[kk] = *(const bf16x8*)(W2 + b0 + kk * 32);
    }
    const int kb1 = (ks < 2) ? ks * 160 : 320 + (ks - 2) * 128;
    const int kc1 = (ks < 2) ? 5 : 4;
    bf16x8 w1r[5];
#pragma unroll
    for (int kk = 0; kk < 5; ++kk) w1r[kk] = (bf16x8){0,0,0,0,0,0,0,0};
    {
        const size_t b0 = (size_t)wr * 1088 + kb1 + ah * 8;
#pragma unroll
        for (int kk = 0; kk < 5; ++kk) if (kk < kc1)
            w1r[kk] = *(const bf16x8*)(W1 + b0 + kk * 32);
    }

    const int jqA = tid >> 8;          // 0..1
    const int bl  = tid & 255;
    const int u0  = 2 * jqA, u1 = u0 + 1;
    float c1a = 0.f, c1b = 0.f, c2a = 0.f, c2b = 0.f;

    const int fc = id & 63, fq = id >> 6;
    const int frow = tid & 63, fkq = tid >> 6;
    __syncthreads();

    unsigned int bidx = 0;

    auto l1_phase = [&](const unsigned short* xsrc, const unsigned short* hsrc,
                        unsigned short* hdst) {
#pragma unroll 1
        for (int np = 0; np < 16; ++np) {
            const int brow = np * 16 + am;
            bf16x8 f[5];
#pragma unroll
            for (int kk = 0; kk < 5; ++kk) if (kk < kc1) {
                const int k = kb1 + kk * 32 + ah * 8;
                f[kk] = (k < 64)
                    ? *(const bf16x8*)(xsrc + (size_t)brow * INDIM + k)
                    : *(const bf16x8*)(hsrc + (size_t)brow * 2048 + (k - 64));
            }
            f32x4 pe = {0,0,0,0}, po = {0,0,0,0};
#pragma unroll
            for (int kk = 0; kk < 5; ++kk) if (kk < kc1) {
                if (kk & 1) po = __builtin_amdgcn_mfma_f32_16x16x32_bf16(w1r[kk], f[kk], po, 0, 0, 0);
                else        pe = __builtin_amdgcn_mfma_f32_16x16x32_bf16(w1r[kk], f[kk], pe, 0, 0, 0);
            }
#pragma unroll
            for (int r = 0; r < 4; ++r)
                part[ks][ah * 4 + r][np * 16 + am] = pe[r] + po[r];
        }
        __syncthreads();
        {
            float g0a = 0.f, g1a = 0.f, g2a = 0.f, g3a = 0.f;
            float g0b = 0.f, g1b = 0.f, g2b = 0.f, g3b = 0.f;
#pragma unroll
            for (int s = 0; s < 8; ++s) {
                g0a += part[s][u0][bl];      g1a += part[s][4 + u0][bl];
                g2a += part[s][8 + u0][bl];  g3a += part[s][12 + u0][bl];
                g0b += part[s][u1][bl];      g1b += part[s][4 + u1][bl];
                g2b += part[s][8 + u1][bl];  g3b += part[s][12 + u1][bl];
            }
            const float gia = sigm(g0a + blds[u0]),      gfa = sigm(g1a + blds[4 + u0]);
            const float gga = tanhf(g2a + blds[8 + u0]), goa = sigm(g3a + blds[12 + u0]);
            c1a = gfa * c1a + gia * gga;
            const float gib = sigm(g0b + blds[u1]),      gfb = sigm(g1b + blds[4 + u1]);
            const float ggb = tanhf(g2b + blds[8 + u1]), gob = sigm(g3b + blds[12 + u1]);
            c1b = gfb * c1b + gib * ggb;
            st_h2(hdst + (size_t)bl * 2048 + jb + u0,
                  f2bf(goa * tanhf(c1a)), f2bf(gob * tanhf(c1b)));
        }
        __syncthreads();
    };

    auto l2_phase = [&](const unsigned short* hsrc, unsigned short* hdst) {
#pragma unroll 1
        for (int np = 0; np < 16; ++np) {
            const int brow = np * 16 + am;
            const unsigned short* bp = hsrc + (size_t)brow * 2048 + ks * 256 + ah * 8;
            bf16x8 f[8];
#pragma unroll
            for (int kk = 0; kk < 8; ++kk)
                f[kk] = *(const bf16x8*)(bp + kk * 32);
            f32x4 pe = {0,0,0,0}, po = {0,0,0,0};
#pragma unroll
            for (int kk = 0; kk < 8; ++kk) {
                if (kk & 1) po = __builtin_amdgcn_mfma_f32_16x16x32_bf16(w2r[kk], f[kk], po, 0, 0, 0);
                else        pe = __builtin_amdgcn_mfma_f32_16x16x32_bf16(w2r[kk], f[kk], pe, 0, 0, 0);
            }
#pragma unroll
            for (int r = 0; r < 4; ++r)
                part[ks][ah * 4 + r][np * 16 + am] = pe[r] + po[r];
        }
        __syncthreads();
        {
            float g0a = 0.f, g1a = 0.f, g2a = 0.f, g3a = 0.f;
            float g0b = 0.f, g1b = 0.f, g2b = 0.f, g3b = 0.f;
#pragma unroll
            for (int s = 0; s < 8; ++s) {
                g0a += part[s][u0][bl];      g1a += part[s][4 + u0][bl];
                g2a += part[s][8 + u0][bl];  g3a += part[s][12 + u0][bl];
                g0b += part[s][u1][bl];      g1b += part[s][4 + u1][bl];
                g2b += part[s][8 + u1][bl];  g3b += part[s][12 + u1][bl];
            }
            const float gia = sigm(g0a + blds[16 + u0]),      gfa = sigm(g1a + blds[20 + u0]);
            const float gga = tanhf(g2a + blds[24 + u0]), goa = sigm(g3a + blds[28 + u0]);
            c2a = gfa * c2a + gia * gga;
            const float gib = sigm(g0b + blds[16 + u1]),      gfb = sigm(g1b + blds[20 + u1]);
            const float ggb = tanhf(g2b + blds[24 + u1]), gob = sigm(g3b + blds[28 + u1]);
            c2b = gfb * c2b + gib * ggb;
            st_h2(hdst + (size_t)bl * 2048 + 1024 + jb + u0,
                  f2bf(goa * tanhf(c2a)), f2bf(gob * tanhf(c2b)));
        }
        __syncthreads();
    };

    auto fold = [&](int tm1, const unsigned short* hsrc) {
        const unsigned short* hp = hsrc + (size_t)(fq * 64 + frow) * 2048 + 1024 + fkq * 128;
        const unsigned short* wp = Wlin + (size_t)fc * 1024 + fkq * 128;
        float p = 0.f;
#pragma unroll
        for (int k = 0; k < 128; k += 8) {
            bf16x8 hv = *(const bf16x8*)(hp + k);
            bf16x8 wv = *(const bf16x8*)(wp + k);
#pragma unroll
            for (int u = 0; u < 8; ++u)
                p += bf2f((unsigned short)hv[u]) * bf2f((unsigned short)wv[u]);
        }
        red[fkq * 64 + frow] = p;
        __syncthreads();
        if (tid < 64) {
            float s = blin[fc];
#pragma unroll
            for (int u = 0; u < 8; ++u) s += red[u * 64 + tid];
            st_f32(&outp[((size_t)(fq * 64 + tid) * TF_SZ + tm1) * OUTDIM + fc], s);
        }
        __syncthreads();
    };

    auto tail_out = [&](int t, const unsigned short* hnew, int do_fb) {
        if (id < 32) {
            unsigned short* h2s = (unsigned short*)&part[0][0][0];   // [8][1024]
            float* xstage = (float*)((char*)&part[0][0][0] + 16384); // [8][64]
            const int rowbase = id * 8;
            for (int i = tid; i < 1024; i += 512) {
                const int rr = i >> 7, k8 = (i & 127) * 8;
                *(bf16x8*)&h2s[rr * 1024 + k8] =
                    *(const bf16x8*)&hnew[(size_t)(rowbase + rr) * 2048 + 1024 + k8];
            }
            __syncthreads();
            const int rl = tid >> 6, col = tid & 63;
            float acc = blin[col];
            const unsigned short* wl = Wlin + (size_t)col * HIDN;
            for (int k = 0; k < HIDN; k += 8) {
                bf16x8 hv = *(const bf16x8*)&h2s[rl * 1024 + k];
                bf16x8 wv = *(const bf16x8*)&wl[k];
#pragma unroll
                for (int u = 0; u < 8; ++u)
                    acc += bf2f((unsigned short)hv[u]) * bf2f((unsigned short)wv[u]);
            }
            st_f32(&outp[((size_t)(rowbase + rl) * TF_SZ + t) * OUTDIM + col], acc);
            if (do_fb) {
                red[rl * 64 + col] = acc;
                __syncthreads();
                float x = bo2i[col];
                const unsigned short* w2 = Wo2i + (size_t)col * OUTDIM;
#pragma unroll 8
                for (int jj = 0; jj < OUTDIM; ++jj)
                    x += red[rl * 64 + jj] * bf2f(w2[jj]);
                xstage[rl * 64 + col] = x;
                __syncthreads();
                if (col < 32) {
                    st_h2(xfut + (size_t)(rowbase + rl) * INDIM + col * 2,
                          f2bf(xstage[rl * 64 + col * 2]),
                          f2bf(xstage[rl * 64 + col * 2 + 1]));
                }
            }
        }
    };

    // ================= schedule =================
    l1_phase(xbf, hh0, hh1);
    gbarrier(bar, ++bidx, grp, xcc, leader);

    for (int t = 0; t < T_SZ - 1; ++t) {
        const unsigned short* hsrc = ((t + 1) & 1) ? hh1 : hh0;
        unsigned short*       hdst = (t & 1) ? hh1 : hh0;
        if (t >= 1) fold(t - 1, hsrc);
        l2_phase(hsrc, hdst);
        l1_phase(xbf + (size_t)(t + 1) * B_SZ * INDIM, hsrc, hdst);
        gbarrier(bar, ++bidx, grp, xcc, leader);
    }

    for (int t = T_SZ - 1; t < TF_SZ; ++t) {
        const unsigned short* hsrc = ((t + 1) & 1) ? hh1 : hh0;
        unsigned short*       hdst = (t & 1) ? hh1 : hh0;
        if (t == T_SZ - 1) fold(t - 1, hsrc);
        l2_phase(hsrc, hdst);
        gbarrier(bar, ++bidx, grp, xcc, leader);
        tail_out(t, hdst, t < TF_SZ - 1);
        if (t < TF_SZ - 1) {
            gbarrier(bar, ++bidx, grp, xcc, leader);
            l1_phase(xfut, hsrc, hdst);
            gbarrier(bar, ++bidx, grp, xcc, leader);
        }
    }
}

__global__ void conv_strided(const float* __restrict__ src,
                             unsigned short* __restrict__ dst,
                             int cols, int dstride, int doff, int total)
{
    const int idx = blockIdx.x * 256 + threadIdx.x;
    if (idx >= total) return;
    const int r = idx / cols, c = idx - r * cols;
    dst[(size_t)r * dstride + doff + c] = f2bf(src[idx]);
}

__global__ void conv_x(const float* __restrict__ src,
                       unsigned short* __restrict__ dst)
{
    const int idx = blockIdx.x * 256 + threadIdx.x;
    const int f = idx & 63, t = (idx >> 6) & 255, b = idx >> 14;
    dst[((size_t)t * B_SZ + b) * INDIM + f] = f2bf(src[idx]);
}

extern "C" void kernel_launch(void* const* d_in, const int* in_sizes, int n_in,
                              void* d_out, int out_size, void* d_ws, size_t ws_size,
                              hipStream_t stream)
{
    const float* input = (const float*)d_in[0];
    const float* W_ih1 = (const float*)d_in[1];
    const float* W_hh1 = (const float*)d_in[2];
    const float* b_ih1 = (const float*)d_in[3];
    const float* b_hh1 = (const float*)d_in[4];
    const float* W_ih2 = (const float*)d_in[5];
    const float* W_hh2 = (const float*)d_in[6];
    const float* b_ih2 = (const float*)d_in[7];
    const float* b_hh2 = (const float*)d_in[8];
    const float* W_lin = (const float*)d_in[9];
    const float* b_lin = (const float*)d_in[10];
    const float* W_o2i = (const float*)d_in[11];
    const float* b_o2i = (const float*)d_in[12];
    float* outp = (float*)d_out;

    char* ws = (char*)d_ws;
    unsigned short* Wcat1 = (unsigned short*)ws; ws += (size_t)4096 * 1088 * 2;
    unsigned short* Wcat2 = (unsigned short*)ws; ws += (size_t)4096 * 2048 * 2;
    unsigned short* Wlinb = (unsigned short*)ws; ws += (size_t)64 * 1024 * 2;
    unsigned short* Wo2ib = (unsigned short*)ws; ws += (size_t)64 * 64 * 2;
    unsigned short* xbf   = (unsigned short*)ws; ws += (size_t)T_SZ * B_SZ * INDIM * 2;
    unsigned short* hh0   = (unsigned short*)ws; ws += (size_t)B_SZ * 2 * HIDN * 2;
    unsigned short* hh1   = (unsigned short*)ws; ws += (size_t)B_SZ * 2 * HIDN * 2;
    unsigned short* xfut  = (unsigned short*)ws; ws += (size_t)B_SZ * INDIM * 2;
    ws = (char*)(((size_t)ws + 255) & ~(size_t)255);
    unsigned int*   bar   = (unsigned int*)ws;   ws += 256;

    conv_strided<<<(4096 * 64 + 255) / 256, 256, 0, stream>>>(W_ih1, Wcat1, 64, 1088, 0, 4096 * 64);
    conv_strided<<<(4096 * 1024 + 255) / 256, 256, 0, stream>>>(W_hh1, Wcat1, 1024, 1088, 64, 4096 * 1024);
    conv_strided<<<(4096 * 1024 + 255) / 256, 256, 0, stream>>>(W_ih2, Wcat2, 1024, 2048, 0, 4096 * 1024);
    conv_strided<<<(4096 * 1024 + 255) / 256, 256, 0, stream>>>(W_hh2, Wcat2, 1024, 2048, 1024, 4096 * 1024);
    conv_strided<<<(64 * 1024 + 255) / 256, 256, 0, stream>>>(W_lin, Wlinb, 1024, 1024, 0, 64 * 1024);
    conv_strided<<<(64 * 64 + 255) / 256, 256, 0, stream>>>(W_o2i, Wo2ib, 64, 64, 0, 64 * 64);
    conv_x<<<(T_SZ * B_SZ * INDIM) / 256, 256, 0, stream>>>(input, xbf);

    hipMemsetAsync(hh0, 0, (size_t)B_SZ * 2 * HIDN * 2, stream);
    hipMemsetAsync(hh1, 0, (size_t)B_SZ * 2 * HIDN * 2, stream);
    hipMemsetAsync(bar, 0, 256, stream);

    void* kargs[] = {
        (void*)&xbf, (void*)&xfut, (void*)&Wcat1, (void*)&Wcat2,
        (void*)&Wlinb, (void*)&Wo2ib,
        (void*)&b_ih1, (void*)&b_hh1, (void*)&b_ih2, (void*)&b_hh2,
        (void*)&b_lin, (void*)&b_o2i,
        (void*)&hh0, (void*)&hh1, (void*)&outp, (void*)&bar
    };
    hipLaunchCooperativeKernel((void*)lstm_persist, dim3(NBLK), dim3(512),
                               kargs, 0, stream);
}

// Round 11
// 14024.406 us; speedup vs baseline: 2.4105x; 1.4522x over previous
//
#include <hip/hip_runtime.h>
#include <hip/hip_bf16.h>

#define B_SZ   256
#define T_SZ   256
#define FUT    32
#define TF_SZ  (T_SZ + FUT)
#define HIDN   1024
#define INDIM  64
#define OUTDIM 64
#define NBLK   256
// s_getreg encoding: id=20 (HW_REG_XCC_ID), offset=0, size=32 -> (31<<11)|20
#define HWREG_XCC ((31u << 11) | 20u)

typedef __attribute__((ext_vector_type(8))) short bf16x8;
typedef __attribute__((ext_vector_type(4))) float f32x4;

__device__ __forceinline__ float bf2f(unsigned short u) {
    union { unsigned int i; float f; } v; v.i = (unsigned int)u << 16; return v.f;
}
__device__ __forceinline__ unsigned short f2bf(float f) {
    union { float f; unsigned int i; } v; v.f = f;
    unsigned int r = v.i + 0x7FFFu + ((v.i >> 16) & 1u);
    return (unsigned short)(r >> 16);
}
__device__ __forceinline__ float sigm(float x) { return 1.0f / (1.0f + __expf(-x)); }

// ---------------------------------------------------------------------------
// Persistent 2-layer LSTM, XCD-LOCAL partition (no cross-XCD coherence).
// Census on HW_REG_XCC_ID assigns: batch slice = physical XCD (32 rows),
// unit group = rank within XCD (32 hidden units x 4 gates = 128 gate rows).
// All h / out / x-feedback producer->consumer pairs share one L2 ->
// plain write-back stores + cached loads + L1-only buffer_inv at a
// 32-block PER-XCD barrier. Weights stream L3 -> regs (25.7 MB/XCD/step).
// 8 XCDs run independent timelines. One barrier per steady step.
// ---------------------------------------------------------------------------
__global__ __attribute__((amdgpu_flat_work_group_size(512, 512),
                          amdgpu_waves_per_eu(2, 2)))
void lstm_persist(
    const unsigned short* __restrict__ xbf,    // [256][256][64]
    unsigned short* __restrict__ xfut,         // [256][64]
    const unsigned short* __restrict__ W1,     // [4096][1088] rows g*1024+j
    const unsigned short* __restrict__ W2,     // [4096][2048]
    const unsigned short* __restrict__ Wlin,   // [64][1024]
    const unsigned short* __restrict__ Wo2i,   // [64][64]
    const float* __restrict__ b_ih1, const float* __restrict__ b_hh1,
    const float* __restrict__ b_ih2, const float* __restrict__ b_hh2,
    const float* __restrict__ blin, const float* __restrict__ bo2i,
    unsigned short* __restrict__ hh0,          // [256][2048] = [h1|h2]
    unsigned short* __restrict__ hh1,
    float* __restrict__ outp,                  // [256][288][64] f32
    unsigned int* __restrict__ bar,            // [xcd*64]=cnt, [xcd*64+16]=flag, [512+xcd]=census
    float* __restrict__ obuf)                  // [256][64] out staging (tail)
{
    __shared__ float part[8][128][33];   // [kslice][gate-slot][batch32+pad]
    __shared__ float blds[256];          // [layer2][gate4][unit32]
    __shared__ unsigned cen[2];

    const int tid  = threadIdx.x;
    const int ks   = tid >> 6;
    const int lane = tid & 63;
    const int am   = lane & 15, ah = lane >> 4;

    if (tid == 0) {
        unsigned xc = __builtin_amdgcn_s_getreg(HWREG_XCC) & 7u;
        unsigned rk = __hip_atomic_fetch_add(&bar[512 + xc], 1u,
                          __ATOMIC_RELAXED, __HIP_MEMORY_SCOPE_AGENT);
        cen[0] = xc; cen[1] = rk & 31u;
    }
    __syncthreads();
    const int xcc  = (int)cen[0];
    const int rank = (int)cen[1];
    const int bs   = xcc * 32;          // batch rows [bs, bs+32)
    const int ub   = rank * 32;         // hidden units [ub, ub+32)
    unsigned int* cnt = bar + xcc * 64;
    unsigned int* flg = bar + xcc * 64 + 16;

    if (tid < 256) {
        const int L = tid >> 7, g = (tid >> 5) & 3, j = tid & 31;
        blds[tid] = L ? (b_ih2[g * HIDN + ub + j] + b_hh2[g * HIDN + ub + j])
                      : (b_ih1[g * HIDN + ub + j] + b_hh1[g * HIDN + ub + j]);
    }
    __syncthreads();

    // epilogue constants: thread -> (row er, unit pair ej0/ej1); c in regs
    const int er  = tid >> 4;            // 0..31 batch row (local)
    const int eup = tid & 15;
    const int ej0 = 2 * eup, ej1 = ej0 + 1;
    const int sj0 = ((ej0 >> 4) << 4) | (ej0 & 15);   // slot base within gate
    const int sj1 = sj0 + 1;
    float c1a = 0.f, c1b = 0.f, c2a = 0.f, c2b = 0.f;

    // fold constants: this block covers cols {rank*2, rank*2+1} x 32 rows
    const int fcq = tid >> 8;            // 0..1
    const int frw = (tid >> 3) & 31;     // 0..31
    const int fkq = tid & 7;             // 0..7 (128-K slice)

    // layer-1 K split per wave (K=1088): ks<2 -> 5 chunks, else 4
    const int kb1 = (ks < 2) ? ks * 160 : 320 + (ks - 2) * 128;
    const int kc1 = (ks < 2) ? 5 : 4;

    unsigned bv = 0;

    auto xbar = [&](unsigned bidx) {
        __syncthreads();
        if (tid == 0) {
            __builtin_amdgcn_fence(__ATOMIC_RELEASE, "workgroup");
            __builtin_amdgcn_s_waitcnt(0);            // stores at L2
            unsigned a = __hip_atomic_fetch_add(cnt, 1u, __ATOMIC_RELAXED,
                                                __HIP_MEMORY_SCOPE_AGENT);
            if (a == bidx * 32u - 1u)
                __hip_atomic_store(flg, bidx, __ATOMIC_RELAXED,
                                   __HIP_MEMORY_SCOPE_AGENT);
            else
                while (__hip_atomic_load(flg, __ATOMIC_RELAXED,
                                         __HIP_MEMORY_SCOPE_AGENT) < bidx)
                    __builtin_amdgcn_s_sleep(1);
            __builtin_amdgcn_fence(__ATOMIC_ACQUIRE, "workgroup");
        }
        __syncthreads();
        asm volatile("buffer_inv\n\ts_waitcnt vmcnt(0)" ::: "memory"); // L1 only
    };

    auto cell_epi = [&](int bb, float& ca, float& cb, unsigned short* dst) {
        float g0 = 0.f, g1 = 0.f, g2 = 0.f, g3 = 0.f;
        float h0 = 0.f, h1v = 0.f, h2v = 0.f, h3 = 0.f;
#pragma unroll
        for (int s = 0; s < 8; ++s) {
            g0 += part[s][     sj0][er]; g1  += part[s][32 + sj0][er];
            g2 += part[s][64 + sj0][er]; g3  += part[s][96 + sj0][er];
            h0 += part[s][     sj1][er]; h1v += part[s][32 + sj1][er];
            h2v+= part[s][64 + sj1][er]; h3  += part[s][96 + sj1][er];
        }
        const float gia = sigm(g0 + blds[bb + ej0]);
        const float gfa = sigm(g1 + blds[bb + 32 + ej0]);
        const float gga = tanhf(g2 + blds[bb + 64 + ej0]);
        const float goa = sigm(g3 + blds[bb + 96 + ej0]);
        ca = gfa * ca + gia * gga;
        const float gib = sigm(h0 + blds[bb + ej1]);
        const float gfb = sigm(h1v + blds[bb + 32 + ej1]);
        const float ggb = tanhf(h2v + blds[bb + 64 + ej1]);
        const float gob = sigm(h3 + blds[bb + 96 + ej1]);
        cb = gfb * cb + gib * ggb;
        const unsigned int w = (unsigned int)f2bf(goa * tanhf(ca)) |
                               ((unsigned int)f2bf(gob * tanhf(cb)) << 16);
        *(unsigned int*)dst = w;
    };

    // ---- layer 2: gates = [h1(t)|h2(t-1)] @ W2^T, K=2048 ----
    auto l2_phase = [&](const unsigned short* hsrc, unsigned short* hdst) {
#pragma unroll 1
        for (int mp = 0; mp < 2; ++mp) {
            f32x4 a00={0,0,0,0}, a01={0,0,0,0}, a10={0,0,0,0}, a11={0,0,0,0};
            f32x4 a20={0,0,0,0}, a21={0,0,0,0}, a30={0,0,0,0}, a31={0,0,0,0};
            const size_t r0 = (size_t)((mp*2    ) * 1024 + ub      + am) * 2048;
            const size_t r1 = (size_t)((mp*2    ) * 1024 + ub + 16 + am) * 2048;
            const size_t r2 = (size_t)((mp*2 + 1) * 1024 + ub      + am) * 2048;
            const size_t r3 = (size_t)((mp*2 + 1) * 1024 + ub + 16 + am) * 2048;
#pragma unroll 2
            for (int kk = 0; kk < 8; ++kk) {
                const int k = ks * 256 + kk * 32 + ah * 8;
                bf16x8 f0 = *(const bf16x8*)(hsrc + (size_t)(bs + am) * 2048 + k);
                bf16x8 f1 = *(const bf16x8*)(hsrc + (size_t)(bs + 16 + am) * 2048 + k);
                bf16x8 w0 = *(const bf16x8*)(W2 + r0 + k);
                bf16x8 w1 = *(const bf16x8*)(W2 + r1 + k);
                bf16x8 w2 = *(const bf16x8*)(W2 + r2 + k);
                bf16x8 w3 = *(const bf16x8*)(W2 + r3 + k);
                a00 = __builtin_amdgcn_mfma_f32_16x16x32_bf16(w0, f0, a00, 0, 0, 0);
                a01 = __builtin_amdgcn_mfma_f32_16x16x32_bf16(w0, f1, a01, 0, 0, 0);
                a10 = __builtin_amdgcn_mfma_f32_16x16x32_bf16(w1, f0, a10, 0, 0, 0);
                a11 = __builtin_amdgcn_mfma_f32_16x16x32_bf16(w1, f1, a11, 0, 0, 0);
                a20 = __builtin_amdgcn_mfma_f32_16x16x32_bf16(w2, f0, a20, 0, 0, 0);
                a21 = __builtin_amdgcn_mfma_f32_16x16x32_bf16(w2, f1, a21, 0, 0, 0);
                a30 = __builtin_amdgcn_mfma_f32_16x16x32_bf16(w3, f0, a30, 0, 0, 0);
                a31 = __builtin_amdgcn_mfma_f32_16x16x32_bf16(w3, f1, a31, 0, 0, 0);
            }
            const int mb = mp * 64;
#pragma unroll
            for (int r = 0; r < 4; ++r) {
                part[ks][mb      + ah*4 + r][am]      = a00[r];
                part[ks][mb      + ah*4 + r][16 + am] = a01[r];
                part[ks][mb + 16 + ah*4 + r][am]      = a10[r];
                part[ks][mb + 16 + ah*4 + r][16 + am] = a11[r];
                part[ks][mb + 32 + ah*4 + r][am]      = a20[r];
                part[ks][mb + 32 + ah*4 + r][16 + am] = a21[r];
                part[ks][mb + 48 + ah*4 + r][am]      = a30[r];
                part[ks][mb + 48 + ah*4 + r][16 + am] = a31[r];
            }
        }
        __syncthreads();
        cell_epi(128, c2a, c2b,
                 hdst + (size_t)(bs + er) * 2048 + 1024 + ub + ej0);
        __syncthreads();
    };

    // ---- layer 1: gates = [x|h1(t-1)] @ W1^T, K=1088 ----
    auto l1_phase = [&](const unsigned short* xsrc, const unsigned short* hsrc,
                        unsigned short* hdst) {
#pragma unroll 1
        for (int mp = 0; mp < 2; ++mp) {
            f32x4 a00={0,0,0,0}, a01={0,0,0,0}, a10={0,0,0,0}, a11={0,0,0,0};
            f32x4 a20={0,0,0,0}, a21={0,0,0,0}, a30={0,0,0,0}, a31={0,0,0,0};
            const size_t r0 = (size_t)((mp*2    ) * 1024 + ub      + am) * 1088;
            const size_t r1 = (size_t)((mp*2    ) * 1024 + ub + 16 + am) * 1088;
            const size_t r2 = (size_t)((mp*2 + 1) * 1024 + ub      + am) * 1088;
            const size_t r3 = (size_t)((mp*2 + 1) * 1024 + ub + 16 + am) * 1088;
#pragma unroll 1
            for (int kk = 0; kk < 5; ++kk) {
                if (kk >= kc1) break;
                const int k = kb1 + kk * 32 + ah * 8;
                bf16x8 f0, f1;
                if (k < 64) {
                    f0 = *(const bf16x8*)(xsrc + (size_t)(bs + am) * INDIM + k);
                    f1 = *(const bf16x8*)(xsrc + (size_t)(bs + 16 + am) * INDIM + k);
                } else {
                    f0 = *(const bf16x8*)(hsrc + (size_t)(bs + am) * 2048 + (k - 64));
                    f1 = *(const bf16x8*)(hsrc + (size_t)(bs + 16 + am) * 2048 + (k - 64));
                }
                bf16x8 w0 = *(const bf16x8*)(W1 + r0 + k);
                bf16x8 w1 = *(const bf16x8*)(W1 + r1 + k);
                bf16x8 w2 = *(const bf16x8*)(W1 + r2 + k);
                bf16x8 w3 = *(const bf16x8*)(W1 + r3 + k);
                a00 = __builtin_amdgcn_mfma_f32_16x16x32_bf16(w0, f0, a00, 0, 0, 0);
                a01 = __builtin_amdgcn_mfma_f32_16x16x32_bf16(w0, f1, a01, 0, 0, 0);
                a10 = __builtin_amdgcn_mfma_f32_16x16x32_bf16(w1, f0, a10, 0, 0, 0);
                a11 = __builtin_amdgcn_mfma_f32_16x16x32_bf16(w1, f1, a11, 0, 0, 0);
                a20 = __builtin_amdgcn_mfma_f32_16x16x32_bf16(w2, f0, a20, 0, 0, 0);
                a21 = __builtin_amdgcn_mfma_f32_16x16x32_bf16(w2, f1, a21, 0, 0, 0);
                a30 = __builtin_amdgcn_mfma_f32_16x16x32_bf16(w3, f0, a30, 0, 0, 0);
                a31 = __builtin_amdgcn_mfma_f32_16x16x32_bf16(w3, f1, a31, 0, 0, 0);
            }
            const int mb = mp * 64;
#pragma unroll
            for (int r = 0; r < 4; ++r) {
                part[ks][mb      + ah*4 + r][am]      = a00[r];
                part[ks][mb      + ah*4 + r][16 + am] = a01[r];
                part[ks][mb + 16 + ah*4 + r][am]      = a10[r];
                part[ks][mb + 16 + ah*4 + r][16 + am] = a11[r];
                part[ks][mb + 32 + ah*4 + r][am]      = a20[r];
                part[ks][mb + 32 + ah*4 + r][16 + am] = a21[r];
                part[ks][mb + 48 + ah*4 + r][am]      = a30[r];
                part[ks][mb + 48 + ah*4 + r][16 + am] = a31[r];
            }
        }
        __syncthreads();
        cell_epi(0, c1a, c1b,
                 hdst + (size_t)(bs + er) * 2048 + ub + ej0);
        __syncthreads();
    };

    // ---- out(tm1) = h2(tm1) @ Wlin^T + blin (2 cols/block, 32 rows) ----
    auto fold = [&](int tm1, const unsigned short* hsrc, int wob) {
        float* red = (float*)&part[0][0][0];   // 512 f32, free at this point
        const int col = rank * 2 + fcq;
        const unsigned short* hp = hsrc + (size_t)(bs + frw) * 2048 + 1024 + fkq * 128;
        const unsigned short* wp = Wlin + (size_t)col * 1024 + fkq * 128;
        float p = 0.f;
#pragma unroll
        for (int k = 0; k < 128; k += 8) {
            bf16x8 hv = *(const bf16x8*)(hp + k);
            bf16x8 wv = *(const bf16x8*)(wp + k);
#pragma unroll
            for (int u = 0; u < 8; ++u)
                p += bf2f((unsigned short)hv[u]) * bf2f((unsigned short)wv[u]);
        }
        red[tid] = p;
        __syncthreads();
        if (tid < 64) {
            const int c2 = rank * 2 + (tid >> 5), rw = tid & 31;
            float s = blin[c2];
#pragma unroll
            for (int u = 0; u < 8; ++u)
                s += red[((tid >> 5) << 8) | (rw << 3) | u];
            outp[((size_t)(bs + rw) * TF_SZ + tm1) * OUTDIM + c2] = s;
            if (wob) obuf[(size_t)(bs + rw) * OUTDIM + c2] = s;
        }
        __syncthreads();
    };

    // ---- x(t+1) = out(t) @ Wo2i^T + bo2i (1 row/block) ----
    auto xfb = [&]() {
        if (tid < 64) {
            const float* orow = obuf + (size_t)(bs + rank) * OUTDIM;
            float x = bo2i[tid];
            const unsigned short* w2 = Wo2i + (size_t)tid * OUTDIM;
#pragma unroll 8
            for (int j = 0; j < OUTDIM; ++j)
                x += orow[j] * bf2f(w2[j]);
            xfut[(size_t)(bs + rank) * INDIM + tid] = f2bf(x);
        }
    };

    // ================= schedule (per-XCD independent) =================
    l1_phase(xbf, hh0, hh1);                       // h1(0)
    xbar(++bv);

    for (int t = 0; t < T_SZ - 1; ++t) {
        const unsigned short* hsrc = ((t + 1) & 1) ? hh1 : hh0;  // h1(t)|h2(t-1)
        unsigned short*       hdst = (t & 1) ? hh1 : hh0;        // h2(t), h1(t+1)
        if (t >= 1) fold(t - 1, hsrc, 0);
        l2_phase(hsrc, hdst);
        l1_phase(xbf + (size_t)(t + 1) * B_SZ * INDIM, hsrc, hdst);
        xbar(++bv);
    }

    for (int t = T_SZ - 1; t < TF_SZ; ++t) {
        const unsigned short* hsrc = ((t + 1) & 1) ? hh1 : hh0;
        unsigned short*       hdst = (t & 1) ? hh1 : hh0;
        if (t == T_SZ - 1) fold(t - 1, hsrc, 0);   // out(254)
        l2_phase(hsrc, hdst);                      // h2(t)
        xbar(++bv);
        fold(t, hdst, (t < TF_SZ - 1) ? 1 : 0);    // out(t) (+obuf)
        if (t < TF_SZ - 1) {
            xbar(++bv);                            // obuf visible
            xfb();                                 // x(t+1)
            xbar(++bv);                            // xfut visible
            l1_phase(xfut, hsrc, hdst);            // h1(t+1)
            xbar(++bv);
        }
    }
}

__global__ void conv_strided(const float* __restrict__ src,
                             unsigned short* __restrict__ dst,
                             int cols, int dstride, int doff, int total)
{
    const int idx = blockIdx.x * 256 + threadIdx.x;
    if (idx >= total) return;
    const int r = idx / cols, c = idx - r * cols;
    dst[(size_t)r * dstride + doff + c] = f2bf(src[idx]);
}

__global__ void conv_x(const float* __restrict__ src,
                       unsigned short* __restrict__ dst)
{
    const int idx = blockIdx.x * 256 + threadIdx.x;
    const int f = idx & 63, t = (idx >> 6) & 255, b = idx >> 14;
    dst[((size_t)t * B_SZ + b) * INDIM + f] = f2bf(src[idx]);
}

extern "C" void kernel_launch(void* const* d_in, const int* in_sizes, int n_in,
                              void* d_out, int out_size, void* d_ws, size_t ws_size,
                              hipStream_t stream)
{
    const float* input = (const float*)d_in[0];
    const float* W_ih1 = (const float*)d_in[1];
    const float* W_hh1 = (const float*)d_in[2];
    const float* b_ih1 = (const float*)d_in[3];
    const float* b_hh1 = (const float*)d_in[4];
    const float* W_ih2 = (const float*)d_in[5];
    const float* W_hh2 = (const float*)d_in[6];
    const float* b_ih2 = (const float*)d_in[7];
    const float* b_hh2 = (const float*)d_in[8];
    const float* W_lin = (const float*)d_in[9];
    const float* b_lin = (const float*)d_in[10];
    const float* W_o2i = (const float*)d_in[11];
    const float* b_o2i = (const float*)d_in[12];
    float* outp = (float*)d_out;

    char* ws = (char*)d_ws;
    unsigned short* Wcat1 = (unsigned short*)ws; ws += (size_t)4096 * 1088 * 2;
    unsigned short* Wcat2 = (unsigned short*)ws; ws += (size_t)4096 * 2048 * 2;
    unsigned short* Wlinb = (unsigned short*)ws; ws += (size_t)64 * 1024 * 2;
    unsigned short* Wo2ib = (unsigned short*)ws; ws += (size_t)64 * 64 * 2;
    unsigned short* xbf   = (unsigned short*)ws; ws += (size_t)T_SZ * B_SZ * INDIM * 2;
    unsigned short* hh0   = (unsigned short*)ws; ws += (size_t)B_SZ * 2 * HIDN * 2;
    unsigned short* hh1   = (unsigned short*)ws; ws += (size_t)B_SZ * 2 * HIDN * 2;
    unsigned short* xfut  = (unsigned short*)ws; ws += (size_t)B_SZ * INDIM * 2;
    ws = (char*)(((size_t)ws + 255) & ~(size_t)255);
    unsigned int*   bar   = (unsigned int*)ws;   ws += 4096;
    float*          obuf  = (float*)ws;          ws += (size_t)B_SZ * OUTDIM * 4;

    conv_strided<<<(4096 * 64 + 255) / 256, 256, 0, stream>>>(W_ih1, Wcat1, 64, 1088, 0, 4096 * 64);
    conv_strided<<<(4096 * 1024 + 255) / 256, 256, 0, stream>>>(W_hh1, Wcat1, 1024, 1088, 64, 4096 * 1024);
    conv_strided<<<(4096 * 1024 + 255) / 256, 256, 0, stream>>>(W_ih2, Wcat2, 1024, 2048, 0, 4096 * 1024);
    conv_strided<<<(4096 * 1024 + 255) / 256, 256, 0, stream>>>(W_hh2, Wcat2, 1024, 2048, 1024, 4096 * 1024);
    conv_strided<<<(64 * 1024 + 255) / 256, 256, 0, stream>>>(W_lin, Wlinb, 1024, 1024, 0, 64 * 1024);
    conv_strided<<<(64 * 64 + 255) / 256, 256, 0, stream>>>(W_o2i, Wo2ib, 64, 64, 0, 64 * 64);
    conv_x<<<(T_SZ * B_SZ * INDIM) / 256, 256, 0, stream>>>(input, xbf);

    hipMemsetAsync(hh0, 0, (size_t)B_SZ * 2 * HIDN * 2, stream);
    hipMemsetAsync(hh1, 0, (size_t)B_SZ * 2 * HIDN * 2, stream);
    hipMemsetAsync(bar, 0, 4096, stream);

    void* kargs[] = {
        (void*)&xbf, (void*)&xfut, (void*)&Wcat1, (void*)&Wcat2,
        (void*)&Wlinb, (void*)&Wo2ib,
        (void*)&b_ih1, (void*)&b_hh1, (void*)&b_ih2, (void*)&b_hh2,
        (void*)&b_lin, (void*)&b_o2i,
        (void*)&hh0, (void*)&hh1, (void*)&outp, (void*)&bar, (void*)&obuf
    };
    hipLaunchCooperativeKernel((void*)lstm_persist, dim3(NBLK), dim3(512),
                               kargs, 0, stream);
}